// Round 8
// baseline (2695.253 us; speedup 1.0000x reference)
//
#include <hip/hip_runtime.h>

#define TT 128
#define BB 64
#define HH 1024
#define LL 4
#define NWG 256
#define NPROD 64u

typedef _Float16 f16;
typedef __attribute__((ext_vector_type(4))) _Float16 f16x4;
typedef __attribute__((ext_vector_type(8))) _Float16 f16x8;
typedef __attribute__((ext_vector_type(4))) float f32x4;
typedef unsigned long long u64;

// ---------------- persistent device buffers ----------------
// Fragment layout for a [64 rows x 1024 k] fp16 tensor (HW-verified r1/r4/r6/r7):
//   flat = ((rg*32 + ktp)*64 + lane)*8 + e
//   rg = row>>4, ktp = k>>5, lane = ((k>>2)&3)<<4 | (row&15), e = ((k>>4)&1)<<2 | (k&3)
// A-frag for v_mfma_f32_16x16x16f16: m = lane&15, k = 4*(lane>>4)+e
__device__ __align__(16) f16 g_in16[TT][65536];           // inputs, frag layout per t
// write-once state slots: slot t+1 holds post-step-t state. Producers publish with
// device-scope atomic stores; consumers read with device-scope atomic loads
// (bypass possibly-stale L1/L2). NO cache-wide fences anywhere (r6/r7-proven).
__device__ __align__(16) f16 g_c16[LL][TT + 1][65536];    // cell state fp16 (feeds next layer)
__device__ __align__(16) f16 g_h16[LL][TT + 1][65536];    // hidden state fp16 (U-matmul input)
__device__ __align__(16) float g_c32[LL][BB][HH];         // cell state master f32 (WG-private)
__device__ unsigned g_done[LL][TT];                       // completion counters (64 WGs each)

// ---------------- init: zero state slot 0 + flags + c32 ----------------
__global__ void k_init() {
  unsigned tid = blockIdx.x * blockDim.x + threadIdx.x;
  unsigned n = gridDim.x * blockDim.x;
  float* c32 = &g_c32[0][0][0];
  for (unsigned i = tid; i < LL * BB * HH; i += n) c32[i] = 0.f;
  for (unsigned i = tid; i < LL * 65536 / 2; i += n) {
    int jj = i >> 15, q = i & 32767;
    ((unsigned*)&g_h16[jj][0][0])[q] = 0u;
  }
  unsigned* pd = &g_done[0][0];
  for (unsigned i = tid; i < LL * TT; i += n) pd[i] = 0u;
}

// ---------------- pack inputs f32 -> fp16 fragment layout (verified) ----------------
__global__ void k_pack_in(const float* __restrict__ inp) {
  int tid = blockIdx.x * blockDim.x + threadIdx.x;
  int t = tid >> 14, q = tid & 16383;
  int row = q >> 8, hu = (q & 255) << 2;
  const float4 x = *(const float4*)(inp + ((size_t)t << 16) + (row << 10) + hu);
  int rg = row >> 4, ktp = hu >> 5;
  int ln = (((hu >> 2) & 3) << 4) | (row & 15);
  int e0 = ((hu >> 4) & 1) << 2;
  f16x4 v = {(f16)x.x, (f16)x.y, (f16)x.z, (f16)x.w};
  *(f16x4*)&g_in16[t][(((rg * 32 + ktp) * 64 + ln) << 3) + e0] = v;
}

// ---------------- main persistent kernel ----------------
__device__ __forceinline__ float sigf(float x) { return 1.f / (1.f + __expf(-x)); }
__device__ __forceinline__ float tanh_(float x) {
  float q = __expf(-2.f * fabsf(x));
  return copysignf((1.f - q) / (1.f + q), x);
}
__device__ __forceinline__ f16x4 lo8(f16x8 v) { return __builtin_shufflevector(v, v, 0, 1, 2, 3); }
__device__ __forceinline__ f16x4 hi8(f16x8 v) { return __builtin_shufflevector(v, v, 4, 5, 6, 7); }
__device__ __forceinline__ void waitflag(const unsigned* p, unsigned n) {
  while (__hip_atomic_load(p, __ATOMIC_RELAXED, __HIP_MEMORY_SCOPE_AGENT) < n)
    __builtin_amdgcn_s_sleep(2);
}
// coherent (device-scope) 16B state load: two u64 atomic loads, bypass stale L1/L2,
// vmcnt-tracked by the compiler (pipelines normally). coh is wave-uniform. (r6-proven)
__device__ __forceinline__ f16x8 ldA(const f16* p, bool coh) {
  if (coh) {
    const u64* q = (const u64*)p;
    union { u64 v[2]; f16x8 h; } u;
    u.v[0] = __hip_atomic_load(q,     __ATOMIC_RELAXED, __HIP_MEMORY_SCOPE_AGENT);
    u.v[1] = __hip_atomic_load(q + 1, __ATOMIC_RELAXED, __HIP_MEMORY_SCOPE_AGENT);
    return u.h;
  }
  return *(const f16x8*)p;
}

#define MFMA16(A_, B_, C_) __builtin_amdgcn_mfma_f32_16x16x16f16(A_, B_, C_, 0, 0, 0)

// Decomposition (r7-proven, duplication-free): WG (j,s) owns 64 rows x 64 gate-cols.
// Wave w: mat = w>>2 (0: x@W, 1: h@U), K-quarter kq = w&3; Wr[32] f16x8 = 128 VGPRs,
// disjoint 32 KB A slice per wave. 8 partials reduced via 64 KiB LDS (two col-phases).
// NEW r8: (a) per-wave dependency waits -- h-waves depend only on own layer t-1, so
// the whole h-GEMM overlaps the x-wait; (b) A-loads in 4 batches of 8 independent
// loads (single vmcnt wait each) -> 4 serialized MALL trips instead of 8.
__global__ __launch_bounds__(512, 2) void k_main(const float* __restrict__ W,
                                                 const float* __restrict__ U,
                                                 const float* __restrict__ bias,
                                                 float* __restrict__ out) {
  const int j = blockIdx.x >> 6, s = blockIdx.x & 63;
  const int tid = threadIdx.x, lane = tid & 63, wv = tid >> 6;
  const int mat = wv >> 2, kq = wv & 3;
  __shared__ float zl[16384];  // [8 waves][64 rows][32 colhalf], swizzled, 64 KiB

  // ---- one-time weight gather f32 -> fp16 regs (r4-verified) ----
  const float* src = (mat ? U : W) + (size_t)j * (HH * 4 * HH);
  const int colb = s * 16 + (lane & 15);
  const int kb0 = kq * 256 + ((lane >> 4) << 2);
  f16x8 Wr[32];
#pragma unroll
  for (int kk = 0; kk < 16; ++kk)
#pragma unroll
    for (int cfp = 0; cfp < 2; ++cfp) {
      f16x8 v;
#pragma unroll
      for (int hf = 0; hf < 2; ++hf)
#pragma unroll
        for (int e = 0; e < 4; ++e)
          v[hf * 4 + e] = (f16)src[(size_t)(kb0 + kk * 16 + e) * 4096 + (cfp * 2 + hf) * 1024 + colb];
      Wr[kk * 2 + cfp] = v;
    }

  // ---- per-thread epilogue constants (r4-verified) ----
  const int row = tid >> 3, hl0 = (tid & 7) * 2;
  const int hu0 = s * 16 + hl0;
  float br[2][4];
#pragma unroll
  for (int el = 0; el < 2; ++el)
#pragma unroll
    for (int g = 0; g < 4; ++g) br[el][g] = bias[j * 4096 + g * 1024 + hu0 + el];
  const int fibase = ((((row >> 4) * 32 + (hu0 >> 5)) * 64 +
                       ((((hu0 >> 2) & 3) << 4) | (row & 15))) << 3) +
                     ((((hu0 >> 4) & 1) << 2) | (hu0 & 3));
  const int fib2 = fibase >> 1;  // u32 index (fibase even: hu0 even)
  unsigned* const hPub = (unsigned*)&g_h16[j][0][0];
  unsigned* const cPub = (unsigned*)&g_c16[j][0][0];
  float* c32p = &g_c32[j][row][hu0];
  const int ktp0 = kq * 8;
  const bool coh = mat || (j > 0);  // in16 is pre-launch constant -> plain loads ok

  for (int t = 0; t < TT; ++t) {
    // ---- per-wave dependency wait (h-waves decouple from x-waves; no fences) ----
    if (mat == 0) {
      if (j > 0) waitflag(&g_done[j - 1][t], NPROD);   // x-side: layer below, step t
    } else {
      if (t > 0) waitflag(&g_done[j][t - 1], NPROD);   // h-side: own layer, step t-1
    }
    asm volatile("" ::: "memory");  // forbid hoisting A loads above the spin

    const f16* Ab = mat ? &g_h16[j][t][0]
                        : (j ? &g_c16[j - 1][t + 1][0] : &g_in16[t][0]);

    f32x4 acc[4][4];
#pragma unroll
    for (int rf = 0; rf < 4; ++rf)
#pragma unroll
      for (int cf = 0; cf < 4; ++cf) acc[rf][cf] = (f32x4){0.f, 0.f, 0.f, 0.f};

    // ---- GEMM: 4 batches of 8 independent loads -> 4 serialized MALL trips ----
#pragma unroll
    for (int kb = 0; kb < 4; ++kb) {
      f16x8 a8[8];
#pragma unroll
      for (int u = 0; u < 8; ++u)
        a8[u] = ldA(Ab + (((u & 3) * 32) + ktp0 + kb * 2 + (u >> 2)) * 512 + lane * 8, coh);
#pragma unroll
      for (int kh2 = 0; kh2 < 2; ++kh2) {
        const int kc = kb * 2 + kh2;
#pragma unroll
        for (int hf = 0; hf < 2; ++hf) {
          f16x4 a4[4];
#pragma unroll
          for (int rf = 0; rf < 4; ++rf)
            a4[rf] = hf ? hi8(a8[kh2 * 4 + rf]) : lo8(a8[kh2 * 4 + rf]);
#pragma unroll
          for (int cf = 0; cf < 4; ++cf) {
            const f16x8 wreg = Wr[(kc * 2 + hf) * 2 + (cf >> 1)];
            const f16x4 b4 = (cf & 1) ? hi8(wreg) : lo8(wreg);
#pragma unroll
            for (int rf = 0; rf < 4; ++rf) acc[rf][cf] = MFMA16(a4[rf], b4, acc[rf][cf]);
          }
        }
      }
    }

    // ---- 8-wave reduction via 64 KiB LDS, two column-phases (r4-verified) ----
    float gsum[2][4];
#pragma unroll
    for (int P = 0; P < 2; ++P) {
      __syncthreads();  // joins x/h waves; protects zl reuse vs previous phase/step
#pragma unroll
      for (int rf = 0; rf < 4; ++rf)
#pragma unroll
        for (int ch = 0; ch < 2; ++ch) {
          const int cf = P * 2 + ch;
#pragma unroll
          for (int ri = 0; ri < 4; ++ri) {
            const int rr = rf * 16 + ((lane >> 4) << 2) + ri;
            const int c2 = ch * 16 + (lane & 15);
            zl[wv * 2048 + rr * 32 + (c2 ^ ((rr & 4) << 2))] = acc[rf][cf][ri];
          }
        }
      __syncthreads();
#pragma unroll
      for (int ch = 0; ch < 2; ++ch) {
        const int idx = row * 32 + ((ch * 16 + hl0) ^ ((row & 4) << 2));
        float sx = 0.f, sy = 0.f;
#pragma unroll
        for (int w = 0; w < 8; ++w) {
          const float2 v = *(const float2*)&zl[w * 2048 + idx];
          sx += v.x; sy += v.y;
        }
        gsum[0][P * 2 + ch] = sx;
        gsum[1][P * 2 + ch] = sy;
      }
    }

    // ---- gates + state update (i,f,g,o) ----
    float cns[2], hns[2];
#pragma unroll
    for (int el = 0; el < 2; ++el) {
      const float zi = gsum[el][0] + br[el][0];
      const float zf = gsum[el][1] + br[el][1];
      const float zg = gsum[el][2] + br[el][2];
      const float zo = gsum[el][3] + br[el][3];
      const float cp = c32p[el];
      const float cn = sigf(zf) * cp + sigf(zi) * tanh_(zg);
      c32p[el] = cn;
      cns[el] = cn;
      hns[el] = sigf(zo) * tanh_(cn);
    }
    {
      union { f16 h[2]; unsigned u; } ph, pc;
      ph.h[0] = (f16)hns[0]; ph.h[1] = (f16)hns[1];
      __hip_atomic_store(hPub + (size_t)(t + 1) * 32768 + fib2, ph.u,
                         __ATOMIC_RELAXED, __HIP_MEMORY_SCOPE_AGENT);
      if (j < 3) {
        pc.h[0] = (f16)cns[0]; pc.h[1] = (f16)cns[1];
        __hip_atomic_store(cPub + (size_t)(t + 1) * 32768 + fib2, pc.u,
                           __ATOMIC_RELAXED, __HIP_MEMORY_SCOPE_AGENT);
      }
      if (j == 3 && t == TT - 1) {
        out[(row << 10) + hu0] = cns[0];
        out[(row << 10) + hu0 + 1] = cns[1];
      }
    }

    // ---- publish: drain device-scope stores, then flag (r6/r7-proven) ----
    asm volatile("s_waitcnt vmcnt(0)" ::: "memory");
    __syncthreads();
    if (tid == 0)
      __hip_atomic_fetch_add(&g_done[j][t], 1u, __ATOMIC_RELAXED, __HIP_MEMORY_SCOPE_AGENT);
  }
}

extern "C" void kernel_launch(void* const* d_in, const int* in_sizes, int n_in,
                              void* d_out, int out_size, void* d_ws, size_t ws_size,
                              hipStream_t stream) {
  const float* inp  = (const float*)d_in[0];
  const float* W    = (const float*)d_in[1];
  const float* U    = (const float*)d_in[2];
  const float* bias = (const float*)d_in[3];
  float* out = (float*)d_out;
  k_init<<<256, 256, 0, stream>>>();
  k_pack_in<<<4096, 512, 0, stream>>>(inp);
  k_main<<<NWG, 512, 0, stream>>>(W, U, bias, out);
}

// Round 9
// 2634.450 us; speedup vs baseline: 1.0231x; 1.0231x over previous
//
#include <hip/hip_runtime.h>

#define TT 128
#define BB 64
#define HH 1024
#define LL 4
#define NWG 256

typedef _Float16 f16;
typedef __attribute__((ext_vector_type(4))) _Float16 f16x4;
typedef __attribute__((ext_vector_type(8))) _Float16 f16x8;
typedef __attribute__((ext_vector_type(4))) float f32x4;
typedef unsigned long long u64;

// ---------------- persistent device buffers ----------------
// Fragment layout for a [64 rows x 1024 k] fp16 tensor (HW-verified r1/r4/r6/r7):
//   flat = ((rg*32 + ktp)*64 + lane)*8 + e
//   rg = row>>4, ktp = k>>5, lane = ((k>>2)&3)<<4 | (row&15), e = ((k>>4)&1)<<2 | (k&3)
// A-frag for v_mfma_f32_16x16x16f16: m = lane&15, k = 4*(lane>>4)+e
__device__ __align__(16) f16 g_in16[TT][65536];           // inputs, frag layout per t
// write-once state slots: slot t+1 holds post-step-t state. Producers publish with
// device-scope atomic stores; consumers read with device-scope atomic loads
// (bypass possibly-stale L1/L2). NO cache-wide fences anywhere (r6/r7-proven).
__device__ __align__(16) f16 g_c16[LL][TT + 1][65536];    // cell state fp16 (feeds next layer)
__device__ __align__(16) f16 g_h16[LL][TT + 1][65536];    // hidden state fp16 (U-matmul input)
__device__ __align__(16) float g_c32[LL][BB][HH];         // cell state master f32 (WG-private)
// per-producer epoch: g_ep[j][s] = t+1 after WG (j,s) finished step t. Plain atomic
// STORE (no RMW -> no same-address serialization); consumers poll their 16 producers.
__device__ unsigned g_ep[LL][64];

// ---------------- init: zero state slot 0 + epochs + c32 ----------------
__global__ void k_init() {
  unsigned tid = blockIdx.x * blockDim.x + threadIdx.x;
  unsigned n = gridDim.x * blockDim.x;
  float* c32 = &g_c32[0][0][0];
  for (unsigned i = tid; i < LL * BB * HH; i += n) c32[i] = 0.f;
  for (unsigned i = tid; i < LL * 65536 / 2; i += n) {
    int jj = i >> 15, q = i & 32767;
    ((unsigned*)&g_h16[jj][0][0])[q] = 0u;
  }
  unsigned* pe = &g_ep[0][0];
  for (unsigned i = tid; i < LL * 64; i += n) pe[i] = 0u;
}

// ---------------- pack inputs f32 -> fp16 fragment layout (verified) ----------------
__global__ void k_pack_in(const float* __restrict__ inp) {
  int tid = blockIdx.x * blockDim.x + threadIdx.x;
  int t = tid >> 14, q = tid & 16383;
  int row = q >> 8, hu = (q & 255) << 2;
  const float4 x = *(const float4*)(inp + ((size_t)t << 16) + (row << 10) + hu);
  int rg = row >> 4, ktp = hu >> 5;
  int ln = (((hu >> 2) & 3) << 4) | (row & 15);
  int e0 = ((hu >> 4) & 1) << 2;
  f16x4 v = {(f16)x.x, (f16)x.y, (f16)x.z, (f16)x.w};
  *(f16x4*)&g_in16[t][(((rg * 32 + ktp) * 64 + ln) << 3) + e0] = v;
}

// ---------------- main persistent kernel ----------------
__device__ __forceinline__ float sigf(float x) { return 1.f / (1.f + __expf(-x)); }
__device__ __forceinline__ float tanh_(float x) {
  float q = __expf(-2.f * fabsf(x));
  return copysignf((1.f - q) / (1.f + q), x);
}
__device__ __forceinline__ f16x4 lo8(f16x8 v) { return __builtin_shufflevector(v, v, 0, 1, 2, 3); }
__device__ __forceinline__ f16x4 hi8(f16x8 v) { return __builtin_shufflevector(v, v, 4, 5, 6, 7); }
// lane-parallel producer-exact wait: lane l polls producer (base16 + (l&15))'s epoch
__device__ __forceinline__ void waitep(const unsigned* ep, unsigned target) {
  for (;;) {
    unsigned e = __hip_atomic_load(ep, __ATOMIC_RELAXED, __HIP_MEMORY_SCOPE_AGENT);
    if (__all((int)(e >= target))) break;
    __builtin_amdgcn_s_sleep(1);
  }
}
// coherent (device-scope) 16B state load: two u64 atomic loads, bypass stale L1/L2,
// vmcnt-tracked by the compiler (pipelines normally). coh is wave-uniform. (r6-proven)
__device__ __forceinline__ f16x8 ldA(const f16* p, bool coh) {
  if (coh) {
    const u64* q = (const u64*)p;
    union { u64 v[2]; f16x8 h; } u;
    u.v[0] = __hip_atomic_load(q,     __ATOMIC_RELAXED, __HIP_MEMORY_SCOPE_AGENT);
    u.v[1] = __hip_atomic_load(q + 1, __ATOMIC_RELAXED, __HIP_MEMORY_SCOPE_AGENT);
    return u.h;
  }
  return *(const f16x8*)p;
}

#define MFMA16(A_, B_, C_) __builtin_amdgcn_mfma_f32_16x16x16f16(A_, B_, C_, 0, 0, 0)
// r5-proven zero-conflict zl swizzle (bijective XOR on 5-bit column, same XOR on read)
#define SWZ(r) ((((r) & 4) << 2) ^ (((r) & 3) << 3))

// Decomposition (r7-proven, duplication-free): WG (j,s) owns 64 rows x 64 gate-cols.
// Wave w: mat = w>>2 (0: x@W, 1: h@U), K-quarter kq = w&3; Wr[32] f16x8 = 128 VGPRs,
// disjoint 32 KB A slice per wave. 8 partials reduced via 64 KiB LDS (two col-phases).
// Sync r9: per-producer epochs; each wave lane-parallel-polls exactly its 16 producers
// (K range [kq*256,(kq+1)*256) <-> producer WGs kq*16..kq*16+15). h-waves depend on own
// layer t-1 (ready one stage early) and overlap the x-wait. Publish = vmcnt drain +
// barrier + single epoch STORE by tid0.
__global__ __launch_bounds__(512, 2) void k_main(const float* __restrict__ W,
                                                 const float* __restrict__ U,
                                                 const float* __restrict__ bias,
                                                 float* __restrict__ out) {
  const int j = blockIdx.x >> 6, s = blockIdx.x & 63;
  const int tid = threadIdx.x, lane = tid & 63, wv = tid >> 6;
  const int mat = wv >> 2, kq = wv & 3;
  __shared__ float zl[16384];  // [8 waves][64 rows][32 colhalf], swizzled, 64 KiB

  // ---- one-time weight gather f32 -> fp16 regs (r4-verified) ----
  const float* src = (mat ? U : W) + (size_t)j * (HH * 4 * HH);
  const int colb = s * 16 + (lane & 15);
  const int kb0 = kq * 256 + ((lane >> 4) << 2);
  f16x8 Wr[32];
#pragma unroll
  for (int kk = 0; kk < 16; ++kk)
#pragma unroll
    for (int cfp = 0; cfp < 2; ++cfp) {
      f16x8 v;
#pragma unroll
      for (int hf = 0; hf < 2; ++hf)
#pragma unroll
        for (int e = 0; e < 4; ++e)
          v[hf * 4 + e] = (f16)src[(size_t)(kb0 + kk * 16 + e) * 4096 + (cfp * 2 + hf) * 1024 + colb];
      Wr[kk * 2 + cfp] = v;
    }

  // ---- per-thread epilogue constants (r4-verified) ----
  const int row = tid >> 3, hl0 = (tid & 7) * 2;
  const int hu0 = s * 16 + hl0;
  float br[2][4];
#pragma unroll
  for (int el = 0; el < 2; ++el)
#pragma unroll
    for (int g = 0; g < 4; ++g) br[el][g] = bias[j * 4096 + g * 1024 + hu0 + el];
  const int fibase = ((((row >> 4) * 32 + (hu0 >> 5)) * 64 +
                       ((((hu0 >> 2) & 3) << 4) | (row & 15))) << 3) +
                     ((((hu0 >> 4) & 1) << 2) | (hu0 & 3));
  const int fib2 = fibase >> 1;  // u32 index (fibase even: hu0 even)
  unsigned* const hPub = (unsigned*)&g_h16[j][0][0];
  unsigned* const cPub = (unsigned*)&g_c16[j][0][0];
  float* c32p = &g_c32[j][row][hu0];
  const int ktp0 = kq * 8;
  const bool coh = mat || (j > 0);  // in16 is pre-launch constant -> plain loads ok
  // my 16 producers' epoch slot for this wave (lanes 16-63 duplicate lanes 0-15)
  const unsigned* epX = (j > 0) ? &g_ep[j - 1][kq * 16 + (lane & 15)] : nullptr;
  const unsigned* epH = &g_ep[j][kq * 16 + (lane & 15)];

  for (int t = 0; t < TT; ++t) {
    // ---- per-wave producer-exact dependency wait (no fences, no RMW flags) ----
    if (mat == 0) {
      if (j > 0) waitep(epX, (unsigned)(t + 1));  // layer below finished step t
    } else {
      if (t > 0) waitep(epH, (unsigned)t);        // own layer finished step t-1
    }
    asm volatile("" ::: "memory");  // forbid hoisting A loads above the poll

    const f16* Ab = mat ? &g_h16[j][t][0]
                        : (j ? &g_c16[j - 1][t + 1][0] : &g_in16[t][0]);
    f16x8 a[2][4];
#pragma unroll
    for (int rf = 0; rf < 4; ++rf)
      a[0][rf] = ldA(Ab + (rf * 32 + ktp0) * 512 + lane * 8, coh);

    f32x4 acc[4][4];
#pragma unroll
    for (int rf = 0; rf < 4; ++rf)
#pragma unroll
      for (int cf = 0; cf < 4; ++cf) acc[rf][cf] = (f32x4){0.f, 0.f, 0.f, 0.f};

#pragma unroll
    for (int kc = 0; kc < 8; ++kc) {
      if (kc < 7) {
#pragma unroll
        for (int rf = 0; rf < 4; ++rf)
          a[(kc + 1) & 1][rf] = ldA(Ab + (rf * 32 + ktp0 + kc + 1) * 512 + lane * 8, coh);
      }
#pragma unroll
      for (int hf = 0; hf < 2; ++hf) {
        f16x4 a4[4];
#pragma unroll
        for (int rf = 0; rf < 4; ++rf)
          a4[rf] = hf ? hi8(a[kc & 1][rf]) : lo8(a[kc & 1][rf]);
#pragma unroll
        for (int cf = 0; cf < 4; ++cf) {
          const f16x8 wreg = Wr[(kc * 2 + hf) * 2 + (cf >> 1)];
          const f16x4 b4 = (cf & 1) ? hi8(wreg) : lo8(wreg);
#pragma unroll
          for (int rf = 0; rf < 4; ++rf) acc[rf][cf] = MFMA16(a4[rf], b4, acc[rf][cf]);
        }
      }
    }

    // ---- 8-wave reduction via 64 KiB LDS, two column-phases (r4-verified) ----
    float gsum[2][4];
#pragma unroll
    for (int P = 0; P < 2; ++P) {
      __syncthreads();  // joins x/h waves; protects zl reuse vs previous phase/step
#pragma unroll
      for (int rf = 0; rf < 4; ++rf)
#pragma unroll
        for (int ch = 0; ch < 2; ++ch) {
          const int cf = P * 2 + ch;
#pragma unroll
          for (int ri = 0; ri < 4; ++ri) {
            const int rr = rf * 16 + ((lane >> 4) << 2) + ri;
            const int c2 = ch * 16 + (lane & 15);
            zl[wv * 2048 + rr * 32 + (c2 ^ SWZ(rr))] = acc[rf][cf][ri];
          }
        }
      __syncthreads();
#pragma unroll
      for (int ch = 0; ch < 2; ++ch) {
        const int idx = row * 32 + ((ch * 16 + hl0) ^ SWZ(row));
        float sx = 0.f, sy = 0.f;
#pragma unroll
        for (int w = 0; w < 8; ++w) {
          const float2 v = *(const float2*)&zl[w * 2048 + idx];
          sx += v.x; sy += v.y;
        }
        gsum[0][P * 2 + ch] = sx;
        gsum[1][P * 2 + ch] = sy;
      }
    }

    // ---- gates + state update (i,f,g,o) ----
    float cns[2], hns[2];
#pragma unroll
    for (int el = 0; el < 2; ++el) {
      const float zi = gsum[el][0] + br[el][0];
      const float zf = gsum[el][1] + br[el][1];
      const float zg = gsum[el][2] + br[el][2];
      const float zo = gsum[el][3] + br[el][3];
      const float cp = c32p[el];
      const float cn = sigf(zf) * cp + sigf(zi) * tanh_(zg);
      c32p[el] = cn;
      cns[el] = cn;
      hns[el] = sigf(zo) * tanh_(cn);
    }
    {
      union { f16 h[2]; unsigned u; } ph, pc;
      ph.h[0] = (f16)hns[0]; ph.h[1] = (f16)hns[1];
      __hip_atomic_store(hPub + (size_t)(t + 1) * 32768 + fib2, ph.u,
                         __ATOMIC_RELAXED, __HIP_MEMORY_SCOPE_AGENT);
      if (j < 3) {
        pc.h[0] = (f16)cns[0]; pc.h[1] = (f16)cns[1];
        __hip_atomic_store(cPub + (size_t)(t + 1) * 32768 + fib2, pc.u,
                           __ATOMIC_RELAXED, __HIP_MEMORY_SCOPE_AGENT);
      }
      if (j == 3 && t == TT - 1) {
        out[(row << 10) + hu0] = cns[0];
        out[(row << 10) + hu0 + 1] = cns[1];
      }
    }

    // ---- publish: drain device-scope stores, barrier, single epoch STORE ----
    asm volatile("s_waitcnt vmcnt(0)" ::: "memory");
    __syncthreads();
    if (tid == 0)
      __hip_atomic_store(&g_ep[j][s], (unsigned)(t + 1),
                         __ATOMIC_RELAXED, __HIP_MEMORY_SCOPE_AGENT);
  }
}

extern "C" void kernel_launch(void* const* d_in, const int* in_sizes, int n_in,
                              void* d_out, int out_size, void* d_ws, size_t ws_size,
                              hipStream_t stream) {
  const float* inp  = (const float*)d_in[0];
  const float* W    = (const float*)d_in[1];
  const float* U    = (const float*)d_in[2];
  const float* bias = (const float*)d_in[3];
  float* out = (float*)d_out;
  k_init<<<256, 256, 0, stream>>>();
  k_pack_in<<<4096, 512, 0, stream>>>(inp);
  k_main<<<NWG, 512, 0, stream>>>(W, U, bias, out);
}

// Round 10
// 2120.628 us; speedup vs baseline: 1.2710x; 1.2423x over previous
//
#include <hip/hip_runtime.h>

#define TT 128
#define BB 64
#define HH 1024
#define LL 4
#define NWG 256

typedef _Float16 f16;
typedef __attribute__((ext_vector_type(4))) _Float16 f16x4;
typedef __attribute__((ext_vector_type(8))) _Float16 f16x8;
typedef __attribute__((ext_vector_type(4))) float f32x4;
typedef unsigned long long u64;

// ---------------- persistent device buffers ----------------
// Fragment layout for a [64 rows x 1024 k] fp16 tensor (HW-verified r1/r4/r6/r7):
//   flat = ((rg*32 + ktp)*64 + lane)*8 + e
//   rg = row>>4, ktp = k>>5, lane = ((k>>2)&3)<<4 | (row&15), e = ((k>>4)&1)<<2 | (k&3)
// A-frag for v_mfma_f32_16x16x16f16: m = lane&15, k = 4*(lane>>4)+e
__device__ __align__(16) f16 g_in16[TT][65536];        // inputs, frag layout per t
// 4-deep rotating state slots (t&3): slot (t+1)&3 holds post-step-t state.
// Total state = 4.2 MB -> MALL-resident (r10 fix: was 135 MB write-once, thrashing L3).
// Producers: device-scope atomic stores; consumers: device-scope atomic loads.
// Slot-reuse safety: before stage t, layer j waits ep[j+1][*] >= t-2 (readers of the
// slot being overwritten have finished). NO cache-wide fences anywhere (r6+-proven).
__device__ __align__(16) f16 g_c16[LL][4][65536];      // cell state fp16 (feeds next layer)
__device__ __align__(16) f16 g_h16[LL][4][65536];      // hidden state fp16 (U-matmul input)
__device__ __align__(16) float g_c32[LL][BB][HH];      // cell state master f32 (WG-private)
// per-producer epoch: g_ep[j][s] = t+1 after WG (j,s) finished step t (atomic STORE).
__device__ unsigned g_ep[LL][64];

// ---------------- init: zero h slot 0 + epochs + c32 ----------------
__global__ void k_init() {
  unsigned tid = blockIdx.x * blockDim.x + threadIdx.x;
  unsigned n = gridDim.x * blockDim.x;
  float* c32 = &g_c32[0][0][0];
  for (unsigned i = tid; i < LL * BB * HH; i += n) c32[i] = 0.f;
  for (unsigned i = tid; i < LL * 32768; i += n) {
    int jj = i >> 15, q = i & 32767;
    ((unsigned*)&g_h16[jj][0][0])[q] = 0u;   // h(0) = 0 (slot 0); c16 slot 0 never read
  }
  unsigned* pe = &g_ep[0][0];
  for (unsigned i = tid; i < LL * 64; i += n) pe[i] = 0u;
}

// ---------------- pack inputs f32 -> fp16 fragment layout (verified) ----------------
__global__ void k_pack_in(const float* __restrict__ inp) {
  int tid = blockIdx.x * blockDim.x + threadIdx.x;
  int t = tid >> 14, q = tid & 16383;
  int row = q >> 8, hu = (q & 255) << 2;
  const float4 x = *(const float4*)(inp + ((size_t)t << 16) + (row << 10) + hu);
  int rg = row >> 4, ktp = hu >> 5;
  int ln = (((hu >> 2) & 3) << 4) | (row & 15);
  int e0 = ((hu >> 4) & 1) << 2;
  f16x4 v = {(f16)x.x, (f16)x.y, (f16)x.z, (f16)x.w};
  *(f16x4*)&g_in16[t][(((rg * 32 + ktp) * 64 + ln) << 3) + e0] = v;
}

// ---------------- main persistent kernel ----------------
__device__ __forceinline__ float sigf(float x) { return 1.f / (1.f + __expf(-x)); }
__device__ __forceinline__ float tanh_(float x) {
  float q = __expf(-2.f * fabsf(x));
  return copysignf((1.f - q) / (1.f + q), x);
}
__device__ __forceinline__ f16x4 lo8(f16x8 v) { return __builtin_shufflevector(v, v, 0, 1, 2, 3); }
__device__ __forceinline__ f16x4 hi8(f16x8 v) { return __builtin_shufflevector(v, v, 4, 5, 6, 7); }
// lane-parallel wait: lane l polls its own producer-epoch slot; exit when all >= target
__device__ __forceinline__ void waitep(const unsigned* ep, unsigned target) {
  for (;;) {
    unsigned e = __hip_atomic_load(ep, __ATOMIC_RELAXED, __HIP_MEMORY_SCOPE_AGENT);
    if (__all((int)(e >= target))) break;
    __builtin_amdgcn_s_sleep(1);
  }
}
// coherent (device-scope) 16B state load: two u64 atomic loads, bypass stale L1/L2,
// vmcnt-tracked by the compiler (pipelines normally). coh is wave-uniform. (r6-proven)
__device__ __forceinline__ f16x8 ldA(const f16* p, bool coh) {
  if (coh) {
    const u64* q = (const u64*)p;
    union { u64 v[2]; f16x8 h; } u;
    u.v[0] = __hip_atomic_load(q,     __ATOMIC_RELAXED, __HIP_MEMORY_SCOPE_AGENT);
    u.v[1] = __hip_atomic_load(q + 1, __ATOMIC_RELAXED, __HIP_MEMORY_SCOPE_AGENT);
    return u.h;
  }
  return *(const f16x8*)p;
}

#define MFMA16(A_, B_, C_) __builtin_amdgcn_mfma_f32_16x16x16f16(A_, B_, C_, 0, 0, 0)
#define SWZ(r) ((((r) & 4) << 2) ^ (((r) & 3) << 3))

// Decomposition (r7/r9-proven): WG (j,s) owns 64 rows x 64 gate-cols. Wave w:
// mat = w>>2 (0: x@W, 1: h@U), K-quarter kq = w&3; Wr[32] f16x8 = 128 VGPRs,
// disjoint 32 KB A slice. 8 partials reduced via 64 KiB LDS (two col-phases).
// r10: 4-deep state slots (MALL-resident) + anti-overwrite wait + 8B publish stores
// (256 epilogue threads x 4 consecutive hu -> one u64 atomic store per array).
__global__ __launch_bounds__(512, 2) void k_main(const float* __restrict__ W,
                                                 const float* __restrict__ U,
                                                 const float* __restrict__ bias,
                                                 float* __restrict__ out) {
  const int j = blockIdx.x >> 6, s = blockIdx.x & 63;
  const int tid = threadIdx.x, lane = tid & 63, wv = tid >> 6;
  const int mat = wv >> 2, kq = wv & 3;
  __shared__ float zl[16384];  // [8 waves][64 rows][32 colhalf], swizzled, 64 KiB

  // ---- one-time weight gather f32 -> fp16 regs (r4-verified) ----
  const float* src = (mat ? U : W) + (size_t)j * (HH * 4 * HH);
  const int colb = s * 16 + (lane & 15);
  const int kb0 = kq * 256 + ((lane >> 4) << 2);
  f16x8 Wr[32];
#pragma unroll
  for (int kk = 0; kk < 16; ++kk)
#pragma unroll
    for (int cfp = 0; cfp < 2; ++cfp) {
      f16x8 v;
#pragma unroll
      for (int hf = 0; hf < 2; ++hf)
#pragma unroll
        for (int e = 0; e < 4; ++e)
          v[hf * 4 + e] = (f16)src[(size_t)(kb0 + kk * 16 + e) * 4096 + (cfp * 2 + hf) * 1024 + colb];
      Wr[kk * 2 + cfp] = v;
    }

  // ---- per-thread epilogue constants (256 active threads x (row, 4 hu)) ----
  const bool act = tid < 256;
  const int row = (tid & 255) >> 2;        // 0..63
  const int hl0q = (tid & 3) * 4;          // 0,4,8,12
  const int hu0 = s * 16 + hl0q;           // 4-aligned
  f32x4 brg[4];
#pragma unroll
  for (int g = 0; g < 4; ++g) brg[g] = *(const f32x4*)&bias[j * 4096 + g * 1024 + hu0];
  // u64 publish index: 4 consecutive hu at 4-aligned hu0 occupy e0..e0+3 of one group
  const int grp = (((row >> 4) * 32 + (hu0 >> 5)) * 64 +
                   ((((hu0 >> 2) & 3) << 4) | (row & 15)));
  const int e0 = ((hu0 >> 4) & 1) << 2;
  const int g64 = grp * 2 + (e0 >> 2);     // u64 index within a slot (slot = 16384 u64)
  u64* const hP = (u64*)&g_h16[j][0][0];
  u64* const cP = (u64*)&g_c16[j][0][0];
  float* const c32p = &g_c32[j][row][hu0];
  const int ktp0 = kq * 8;
  const bool coh = mat || (j > 0);  // in16 is pre-launch constant -> plain loads ok
  const unsigned* epX = (j > 0) ? &g_ep[j - 1][kq * 16 + (lane & 15)] : nullptr;
  const unsigned* epH = &g_ep[j][kq * 16 + (lane & 15)];
  const unsigned* epA = (j < 3) ? &g_ep[j + 1][lane] : nullptr;  // anti-overwrite, 64-wide

  for (int t = 0; t < TT; ++t) {
    // ---- per-wave dependency waits (no fences, no RMW flags; r9-proven) ----
    if (mat == 0) {
      if (j > 0) waitep(epX, (unsigned)(t + 1));       // layer below finished step t
    } else {
      if (t > 0) waitep(epH, (unsigned)t);             // own layer finished step t-1
      if (j < 3 && t >= 2) waitep(epA, (unsigned)(t - 2));  // slot-reuse: consumers done
    }
    asm volatile("" ::: "memory");  // forbid hoisting A loads above the polls

    const f16* Ab = mat ? &g_h16[j][t & 3][0]
                        : (j ? &g_c16[j - 1][(t + 1) & 3][0] : &g_in16[t][0]);
    f16x8 a[2][4];
#pragma unroll
    for (int rf = 0; rf < 4; ++rf)
      a[0][rf] = ldA(Ab + (rf * 32 + ktp0) * 512 + lane * 8, coh);

    f32x4 acc[4][4];
#pragma unroll
    for (int rf = 0; rf < 4; ++rf)
#pragma unroll
      for (int cf = 0; cf < 4; ++cf) acc[rf][cf] = (f32x4){0.f, 0.f, 0.f, 0.f};

#pragma unroll
    for (int kc = 0; kc < 8; ++kc) {
      if (kc < 7) {
#pragma unroll
        for (int rf = 0; rf < 4; ++rf)
          a[(kc + 1) & 1][rf] = ldA(Ab + (rf * 32 + ktp0 + kc + 1) * 512 + lane * 8, coh);
      }
#pragma unroll
      for (int hf = 0; hf < 2; ++hf) {
        f16x4 a4[4];
#pragma unroll
        for (int rf = 0; rf < 4; ++rf)
          a4[rf] = hf ? hi8(a[kc & 1][rf]) : lo8(a[kc & 1][rf]);
#pragma unroll
        for (int cf = 0; cf < 4; ++cf) {
          const f16x8 wreg = Wr[(kc * 2 + hf) * 2 + (cf >> 1)];
          const f16x4 b4 = (cf & 1) ? hi8(wreg) : lo8(wreg);
#pragma unroll
          for (int rf = 0; rf < 4; ++rf) acc[rf][cf] = MFMA16(a4[rf], b4, acc[rf][cf]);
        }
      }
    }

    // ---- 8-wave reduction via 64 KiB LDS, two column-phases ----
    float gsum[4][4];  // [el 0..3][gate]
#pragma unroll
    for (int P = 0; P < 2; ++P) {
      __syncthreads();  // joins x/h waves; protects zl reuse vs previous phase/step
#pragma unroll
      for (int rf = 0; rf < 4; ++rf)
#pragma unroll
        for (int ch = 0; ch < 2; ++ch) {
          const int cf = P * 2 + ch;
#pragma unroll
          for (int ri = 0; ri < 4; ++ri) {
            const int rr = rf * 16 + ((lane >> 4) << 2) + ri;
            const int c2 = ch * 16 + (lane & 15);
            zl[wv * 2048 + rr * 32 + (c2 ^ SWZ(rr))] = acc[rf][cf][ri];
          }
        }
      __syncthreads();
      if (act) {
#pragma unroll
        for (int ch = 0; ch < 2; ++ch) {
          const int g = P * 2 + ch;
          const int swcol = (ch * 16 + hl0q) ^ SWZ(row);  // 4-aligned (SWZ hits bits 3-4)
          f32x4 ss = (f32x4){0.f, 0.f, 0.f, 0.f};
#pragma unroll
          for (int w = 0; w < 8; ++w) ss += *(const f32x4*)&zl[w * 2048 + row * 32 + swcol];
#pragma unroll
          for (int el = 0; el < 4; ++el) gsum[el][g] = ss[el];
        }
      }
    }

    // ---- gates + state update (i,f,g,o); 8B coherent publish ----
    if (act) {
      const f32x4 cp = *(const f32x4*)c32p;
      f32x4 cn, hn;
#pragma unroll
      for (int el = 0; el < 4; ++el) {
        const float zi = gsum[el][0] + brg[0][el];
        const float zf = gsum[el][1] + brg[1][el];
        const float zg = gsum[el][2] + brg[2][el];
        const float zo = gsum[el][3] + brg[3][el];
        cn[el] = sigf(zf) * cp[el] + sigf(zi) * tanh_(zg);
        hn[el] = sigf(zo) * tanh_(cn[el]);
      }
      *(f32x4*)c32p = cn;
      union { f16 h[4]; u64 u; } ph, pc;
#pragma unroll
      for (int el = 0; el < 4; ++el) { ph.h[el] = (f16)hn[el]; pc.h[el] = (f16)cn[el]; }
      const int slot = (t + 1) & 3;
      __hip_atomic_store(hP + (size_t)slot * 16384 + g64, ph.u,
                         __ATOMIC_RELAXED, __HIP_MEMORY_SCOPE_AGENT);
      if (j < 3)
        __hip_atomic_store(cP + (size_t)slot * 16384 + g64, pc.u,
                           __ATOMIC_RELAXED, __HIP_MEMORY_SCOPE_AGENT);
      if (j == 3 && t == TT - 1) *(f32x4*)&out[(row << 10) + hu0] = cn;
    }

    // ---- publish: drain device-scope stores, barrier, single epoch STORE ----
    asm volatile("s_waitcnt vmcnt(0)" ::: "memory");
    __syncthreads();
    if (tid == 0)
      __hip_atomic_store(&g_ep[j][s], (unsigned)(t + 1),
                         __ATOMIC_RELAXED, __HIP_MEMORY_SCOPE_AGENT);
  }
}

extern "C" void kernel_launch(void* const* d_in, const int* in_sizes, int n_in,
                              void* d_out, int out_size, void* d_ws, size_t ws_size,
                              hipStream_t stream) {
  const float* inp  = (const float*)d_in[0];
  const float* W    = (const float*)d_in[1];
  const float* U    = (const float*)d_in[2];
  const float* bias = (const float*)d_in[3];
  float* out = (float*)d_out;
  k_init<<<256, 256, 0, stream>>>();
  k_pack_in<<<4096, 512, 0, stream>>>(inp);
  k_main<<<NWG, 512, 0, stream>>>(W, U, bias, out);
}